// Round 3
// baseline (721.123 us; speedup 1.0000x reference)
//
#include <hip/hip_runtime.h>

// EdgeGate: out[e] = silu(f(e) @ W1 + b1) @ W2 + b2,
//   f(e) = [|H_u - H_v| (128), H_u*H_v (128), S_e, F_e]   (258)
//
// R3: miss-count bound, not byte bound (R2: FETCH 1.47GB ~= 1.2KB/row-read,
// 3.3 TB/s random-access ceiling, MfmaUtil 2.6%).
//  - NEW: device-side counting sort of edges by u (hist/scan/scatter into d_ws).
//    Sorted order makes the u-side gather L1/L2-resident (deg~24 reuse);
//    records carry (u, v, orig_e, f16-packed S,F). Output scatters to out[orig_e].
//  - H converted once to f16 in d_ws (gather rows 256 B).
//  - f16 MFMA 16x16x32; K permuted so one half8 of H_u/H_v feeds a chunk-pair.
//  - W1[0:256] f16-transposed in 64 KiB LDS, XOR-swizzled; rows 256/257 + b1 +
//    silu + W2 dot in fp32 epilogue.
//  - Fallback to the R2 unsorted path if ws_size is too small.

typedef _Float16       half8   __attribute__((ext_vector_type(8)));
typedef _Float16       half4v  __attribute__((ext_vector_type(4)));
typedef unsigned short ushort8 __attribute__((ext_vector_type(8)));
typedef float          f32x4   __attribute__((ext_vector_type(4)));

#define TILE_E   128
#define NBLOCKS  512

__device__ __forceinline__ float silu_f(float x) {
    return x / (1.0f + __expf(-x));
}

// ---------------- pre-passes ----------------

__global__ __launch_bounds__(256)
void cvt_h_kernel(const float* __restrict__ H, _Float16* __restrict__ Hh, int n4) {
    int i = blockIdx.x * blockDim.x + threadIdx.x;
    if (i < n4) {
        const float4 f = ((const float4*)H)[i];
        half4v h;
        h[0] = (_Float16)f.x; h[1] = (_Float16)f.y;
        h[2] = (_Float16)f.z; h[3] = (_Float16)f.w;
        ((half4v*)Hh)[i] = h;
    }
}

__global__ __launch_bounds__(256)
void hist_kernel(const int* __restrict__ eidx, int* __restrict__ hist, int E) {
    int e = blockIdx.x * blockDim.x + threadIdx.x;
    if (e < E) atomicAdd(&hist[eidx[e]], 1);
}

__global__ __launch_bounds__(1024)
void scan_kernel(int* __restrict__ hist, int nBins) {
    __shared__ int sums[1024];
    const int t = threadIdx.x;
    const int chunk = (nBins + 1023) / 1024;
    const int lo = t * chunk;
    const int hi = min(lo + chunk, nBins);
    int s = 0;
    for (int i = lo; i < hi; ++i) s += hist[i];
    sums[t] = s;
    __syncthreads();
    for (int off = 1; off < 1024; off <<= 1) {
        int v = (t >= off) ? sums[t - off] : 0;
        __syncthreads();
        sums[t] += v;
        __syncthreads();
    }
    int base = (t == 0) ? 0 : sums[t - 1];
    for (int i = lo; i < hi; ++i) { int c = hist[i]; hist[i] = base; base += c; }
}

__global__ __launch_bounds__(256)
void scatter_kernel(const int* __restrict__ eidx, const float* __restrict__ Se,
                    const float* __restrict__ Fe, int* __restrict__ ofs,
                    int4* __restrict__ recs, int E) {
    int e = blockIdx.x * blockDim.x + threadIdx.x;
    if (e < E) {
        const int u = eidx[e];
        const int v = eidx[E + e];
        const int pos = atomicAdd(&ofs[u], 1);
        _Float16 sh = (_Float16)Se[e];
        _Float16 fh = (_Float16)Fe[e];
        unsigned pk = (unsigned)*(unsigned short*)&sh
                    | ((unsigned)*(unsigned short*)&fh << 16);
        recs[pos] = make_int4(u, v, e, (int)pk);
    }
}

// ---------------- main kernel (sorted records) ----------------
// K-permutation (kp in [0,256)): kp = c*32 + q*8 + j.
// Source dim d = (c>>1)*32 + q*8 + (c&1)*4 + (j>>1); j even -> |diff| row d,
// j odd -> prod row 128+d. Per chunk-pair a lane needs one half8 of each row.

__device__ __forceinline__ void stage_w1(const float* __restrict__ W1,
                                         _Float16* __restrict__ w1t, int tid) {
    const int n = tid & 127;
    const int g = tid >> 7;
    #pragma unroll
    for (int i = 0; i < 8; ++i) {
        const int kb = g + (i << 2);
        half8 tmp;
        #pragma unroll
        for (int j = 0; j < 8; ++j) {
            const int kp = (kb << 3) + j;
            const int c  = kp >> 5;
            const int r5 = kp & 31;
            const int qq = r5 >> 3;
            const int jj = r5 & 7;
            const int d  = ((c >> 1) << 5) + (qq << 3) + ((c & 1) << 2) + (jj >> 1);
            const int src = ((jj & 1) << 7) + d;
            tmp[j] = (_Float16)W1[src * 128 + n];
        }
        *(half8*)&w1t[n * 256 + ((kb ^ (n & 7)) << 3)] = tmp;
    }
}

__global__ __launch_bounds__(512, 4)
void edgegate_sorted(const _Float16* __restrict__ Hh,
                     const int4*  __restrict__ recs,
                     const float* __restrict__ W1,
                     const float* __restrict__ b1,
                     const float* __restrict__ W2,
                     const float* __restrict__ b2,
                     float*       __restrict__ out,
                     int E, int ntiles)
{
    __shared__ _Float16 w1t[128 * 256];   // 64 KiB
    const int tid = threadIdx.x;
    stage_w1(W1, w1t, tid);
    __syncthreads();

    const int lane = tid & 63;
    const int wave = tid >> 6;
    const int q    = lane >> 4;
    const int cb   = lane & 15;
    const int swz  = cb & 7;

    const int cpb   = (ntiles + gridDim.x - 1) / gridDim.x;
    const int tile0 = blockIdx.x * cpb;
    const int tile1 = min(tile0 + cpb, ntiles);

    for (int tile = tile0; tile < tile1; ++tile) {
        const int ebase = tile * TILE_E + wave * 16;
        const int e = min(ebase + cb, E - 1);     // clamp; stores guarded
        const int4 r = recs[e];
        const int u = r.x, v = r.y, oe = r.z;
        const unsigned pk = (unsigned)r.w;
        const unsigned short sl = (unsigned short)(pk & 0xFFFF);
        const unsigned short fl = (unsigned short)(pk >> 16);
        const float Sf = (float)*(const _Float16*)&sl;
        const float Ff = (float)*(const _Float16*)&fl;

        const _Float16* up = Hh + (size_t)u * 128;
        const _Float16* vp = Hh + (size_t)v * 128;

        f32x4 acc[8];
        #pragma unroll
        for (int t = 0; t < 8; ++t) acc[t] = (f32x4){0.f, 0.f, 0.f, 0.f};

        #pragma unroll
        for (int c8 = 0; c8 < 4; ++c8) {
            const half8 u8 = *(const half8*)(up + (c8 << 5) + (q << 3));
            const half8 v8 = *(const half8*)(vp + (c8 << 5) + (q << 3));
            half8 d8 = u8 - v8;
            ushort8 du = *(ushort8*)&d8;
            du = du & (unsigned short)0x7FFF;
            const half8 da = *(half8*)&du;
            const half8 p8 = u8 * v8;

            half8 ae, ao;
            ae[0]=da[0]; ae[1]=p8[0]; ae[2]=da[1]; ae[3]=p8[1];
            ae[4]=da[2]; ae[5]=p8[2]; ae[6]=da[3]; ae[7]=p8[3];
            ao[0]=da[4]; ao[1]=p8[4]; ao[2]=da[5]; ao[3]=p8[5];
            ao[4]=da[6]; ao[5]=p8[6]; ao[6]=da[7]; ao[7]=p8[7];

            const int kb0 = (((c8 << 1) + 0) * 4 + q) ^ swz;
            const int kb1 = (((c8 << 1) + 1) * 4 + q) ^ swz;
            #pragma unroll
            for (int t = 0; t < 8; ++t) {
                const half8 b0 = *(const half8*)&w1t[((t << 4) + cb) * 256 + (kb0 << 3)];
                acc[t] = __builtin_amdgcn_mfma_f32_16x16x32_f16(ae, b0, acc[t], 0, 0, 0);
            }
            #pragma unroll
            for (int t = 0; t < 8; ++t) {
                const half8 b1f = *(const half8*)&w1t[((t << 4) + cb) * 256 + (kb1 << 3)];
                acc[t] = __builtin_amdgcn_mfma_f32_16x16x32_f16(ao, b1f, acc[t], 0, 0, 0);
            }
        }

        // epilogue: per-quad row data comes from lanes cb = q*4+r via shuffle
        float s_r[4], f_r[4]; int oe_r[4];
        #pragma unroll
        for (int rr = 0; rr < 4; ++rr) {
            const int src = (q << 2) + rr;
            s_r[rr]  = __shfl(Sf, src);
            f_r[rr]  = __shfl(Ff, src);
            oe_r[rr] = __shfl(oe, src);
        }

        float rs[4] = {0.f, 0.f, 0.f, 0.f};
        #pragma unroll
        for (int t = 0; t < 8; ++t) {
            const int col    = (t << 4) + cb;
            const float w256 = W1[32768 + col];
            const float w257 = W1[32896 + col];
            const float b1c  = b1[col];
            const float w2c  = W2[col];
            const f32x4 av = acc[t];
            #pragma unroll
            for (int rr = 0; rr < 4; ++rr)
                rs[rr] += silu_f(av[rr] + s_r[rr] * w256 + f_r[rr] * w257 + b1c) * w2c;
        }

        #pragma unroll
        for (int off = 1; off < 16; off <<= 1) {
            #pragma unroll
            for (int rr = 0; rr < 4; ++rr) rs[rr] += __shfl_xor(rs[rr], off);
        }

        if (cb == 0) {
            const float b2v = b2[0];
            #pragma unroll
            for (int rr = 0; rr < 4; ++rr) {
                const int pe = ebase + (q << 2) + rr;
                if (pe < E) out[oe_r[rr]] = rs[rr] + b2v;
            }
        }
    }
}

// ---------------- fallback (R2 unsorted) ----------------

template<bool F16>
__global__ __launch_bounds__(512, 4)
void edgegate_kernel(const float* __restrict__ H,
                     const _Float16* __restrict__ Hh,
                     const int*   __restrict__ eidx,
                     const float* __restrict__ Se,
                     const float* __restrict__ Fe,
                     const float* __restrict__ W1,
                     const float* __restrict__ b1,
                     const float* __restrict__ W2,
                     const float* __restrict__ b2,
                     float*       __restrict__ out,
                     int E, int ntiles)
{
    __shared__ _Float16 w1t[128 * 256];
    const int tid = threadIdx.x;
    stage_w1(W1, w1t, tid);
    __syncthreads();

    const int lane = tid & 63;
    const int wave = tid >> 6;
    const int q    = lane >> 4;
    const int cb   = lane & 15;
    const int swz  = cb & 7;

    for (int tile = blockIdx.x; tile < ntiles; tile += gridDim.x) {
        const int ebase = tile * TILE_E + wave * 16;
        int e = ebase + cb;
        if (e >= E) e = E - 1;
        const int u = eidx[e];
        const int v = eidx[E + e];

        f32x4 acc[8];
        #pragma unroll
        for (int t = 0; t < 8; ++t) acc[t] = (f32x4){0.f, 0.f, 0.f, 0.f};

        #pragma unroll
        for (int c8 = 0; c8 < 4; ++c8) {
            half8 ae, ao;
            if constexpr (F16) {
                const _Float16* up = Hh + (size_t)u * 128;
                const _Float16* vp = Hh + (size_t)v * 128;
                const half8 u8 = *(const half8*)(up + (c8 << 5) + (q << 3));
                const half8 v8 = *(const half8*)(vp + (c8 << 5) + (q << 3));
                half8 d8 = u8 - v8;
                ushort8 du = *(ushort8*)&d8;
                du = du & (unsigned short)0x7FFF;
                const half8 da = *(half8*)&du;
                const half8 p8 = u8 * v8;
                ae[0]=da[0]; ae[1]=p8[0]; ae[2]=da[1]; ae[3]=p8[1];
                ae[4]=da[2]; ae[5]=p8[2]; ae[6]=da[3]; ae[7]=p8[3];
                ao[0]=da[4]; ao[1]=p8[4]; ao[2]=da[5]; ao[3]=p8[5];
                ao[4]=da[6]; ao[5]=p8[6]; ao[6]=da[7]; ao[7]=p8[7];
            } else {
                const float* up = H + (size_t)u * 128;
                const float* vp = H + (size_t)v * 128;
                const float4 uu0 = *(const float4*)(up + (c8 << 5) + (q << 3));
                const float4 vv0 = *(const float4*)(vp + (c8 << 5) + (q << 3));
                const float4 uu1 = *(const float4*)(up + (c8 << 5) + (q << 3) + 4);
                const float4 vv1 = *(const float4*)(vp + (c8 << 5) + (q << 3) + 4);
                ae[0]=(_Float16)fabsf(uu0.x-vv0.x); ae[1]=(_Float16)(uu0.x*vv0.x);
                ae[2]=(_Float16)fabsf(uu0.y-vv0.y); ae[3]=(_Float16)(uu0.y*vv0.y);
                ae[4]=(_Float16)fabsf(uu0.z-vv0.z); ae[5]=(_Float16)(uu0.z*vv0.z);
                ae[6]=(_Float16)fabsf(uu0.w-vv0.w); ae[7]=(_Float16)(uu0.w*vv0.w);
                ao[0]=(_Float16)fabsf(uu1.x-vv1.x); ao[1]=(_Float16)(uu1.x*vv1.x);
                ao[2]=(_Float16)fabsf(uu1.y-vv1.y); ao[3]=(_Float16)(uu1.y*vv1.y);
                ao[4]=(_Float16)fabsf(uu1.z-vv1.z); ao[5]=(_Float16)(uu1.z*vv1.z);
                ao[6]=(_Float16)fabsf(uu1.w-vv1.w); ao[7]=(_Float16)(uu1.w*vv1.w);
            }
            const int kb0 = (((c8 << 1) + 0) * 4 + q) ^ swz;
            const int kb1 = (((c8 << 1) + 1) * 4 + q) ^ swz;
            #pragma unroll
            for (int t = 0; t < 8; ++t) {
                const half8 b0 = *(const half8*)&w1t[((t << 4) + cb) * 256 + (kb0 << 3)];
                acc[t] = __builtin_amdgcn_mfma_f32_16x16x32_f16(ae, b0, acc[t], 0, 0, 0);
            }
            #pragma unroll
            for (int t = 0; t < 8; ++t) {
                const half8 b1f = *(const half8*)&w1t[((t << 4) + cb) * 256 + (kb1 << 3)];
                acc[t] = __builtin_amdgcn_mfma_f32_16x16x32_f16(ao, b1f, acc[t], 0, 0, 0);
            }
        }

        const int e0  = ebase + (q << 2);
        const int e0c = (e0 + 3 < E) ? e0 : (E - 4);
        const float4 s4 = *(const float4*)(Se + e0c);
        const float4 f4 = *(const float4*)(Fe + e0c);

        float rs0 = 0.f, rs1 = 0.f, rs2 = 0.f, rs3 = 0.f;
        #pragma unroll
        for (int t = 0; t < 8; ++t) {
            const int col    = (t << 4) + cb;
            const float w256 = W1[32768 + col];
            const float w257 = W1[32896 + col];
            const float b1c  = b1[col];
            const float w2c  = W2[col];
            const f32x4 av = acc[t];
            rs0 += silu_f(av[0] + s4.x * w256 + f4.x * w257 + b1c) * w2c;
            rs1 += silu_f(av[1] + s4.y * w256 + f4.y * w257 + b1c) * w2c;
            rs2 += silu_f(av[2] + s4.z * w256 + f4.z * w257 + b1c) * w2c;
            rs3 += silu_f(av[3] + s4.w * w256 + f4.w * w257 + b1c) * w2c;
        }
        #pragma unroll
        for (int off = 1; off < 16; off <<= 1) {
            rs0 += __shfl_xor(rs0, off);
            rs1 += __shfl_xor(rs1, off);
            rs2 += __shfl_xor(rs2, off);
            rs3 += __shfl_xor(rs3, off);
        }
        if (cb == 0 && e0 < E) {
            const float b2v = b2[0];
            out[e0]     = rs0 + b2v;
            out[e0 + 1] = rs1 + b2v;
            out[e0 + 2] = rs2 + b2v;
            out[e0 + 3] = rs3 + b2v;
        }
    }
}

// ---------------- launch ----------------

static inline size_t align256(size_t x) { return (x + 255) & ~(size_t)255; }

extern "C" void kernel_launch(void* const* d_in, const int* in_sizes, int n_in,
                              void* d_out, int out_size, void* d_ws, size_t ws_size,
                              hipStream_t stream)
{
    const float* H    = (const float*)d_in[0];
    const int*   eidx = (const int*)  d_in[1];
    const float* Se   = (const float*)d_in[2];
    const float* Fe   = (const float*)d_in[3];
    const float* W1   = (const float*)d_in[4];
    const float* b1   = (const float*)d_in[5];
    const float* W2   = (const float*)d_in[6];
    const float* b2   = (const float*)d_in[7];
    float* out = (float*)d_out;

    const int nH     = in_sizes[0];            // 6.4M floats
    const int nNodes = nH / 128;               // 50000
    const int E      = in_sizes[2];            // 600000
    const int ntiles = (E + TILE_E - 1) / TILE_E;
    const int grid   = (NBLOCKS < ntiles) ? NBLOCKS : ntiles;

    const size_t hhB   = (size_t)nH * sizeof(_Float16);
    const size_t off_h = 0;
    const size_t off_g = align256(hhB);                       // hist
    const size_t off_r = align256(off_g + (size_t)nNodes * 4);// recs
    const size_t need  = off_r + (size_t)E * sizeof(int4);

    if (ws_size >= need) {
        _Float16* Hh  = (_Float16*)((char*)d_ws + off_h);
        int*      hist= (int*)     ((char*)d_ws + off_g);
        int4*     recs= (int4*)    ((char*)d_ws + off_r);

        const int n4 = nH / 4;
        hipLaunchKernelGGL(cvt_h_kernel, dim3((n4 + 255) / 256), dim3(256), 0, stream,
                           H, Hh, n4);
        hipMemsetAsync(hist, 0, (size_t)nNodes * 4, stream);
        hipLaunchKernelGGL(hist_kernel, dim3((E + 255) / 256), dim3(256), 0, stream,
                           eidx, hist, E);
        hipLaunchKernelGGL(scan_kernel, dim3(1), dim3(1024), 0, stream,
                           hist, nNodes);
        hipLaunchKernelGGL(scatter_kernel, dim3((E + 255) / 256), dim3(256), 0, stream,
                           eidx, Se, Fe, hist, recs, E);
        hipLaunchKernelGGL(edgegate_sorted, dim3(grid), dim3(512), 0, stream,
                           Hh, recs, W1, b1, W2, b2, out, E, ntiles);
    } else if (ws_size >= hhB) {
        _Float16* Hh = (_Float16*)d_ws;
        const int n4 = nH / 4;
        hipLaunchKernelGGL(cvt_h_kernel, dim3((n4 + 255) / 256), dim3(256), 0, stream,
                           H, Hh, n4);
        hipLaunchKernelGGL((edgegate_kernel<true>), dim3(grid), dim3(512), 0, stream,
                           H, Hh, eidx, Se, Fe, W1, b1, W2, b2, out, E, ntiles);
    } else {
        hipLaunchKernelGGL((edgegate_kernel<false>), dim3(grid), dim3(512), 0, stream,
                           H, (const _Float16*)nullptr, eidx, Se, Fe, W1, b1, W2, b2,
                           out, E, ntiles);
    }
}